// Round 1
// baseline (172.905 us; speedup 1.0000x reference)
//
#include <hip/hip_runtime.h>
#include <math.h>

#define L_  8192
#define D_  512
#define E_  8
#define DE_ 4096      // D_*E_
#define C_  128       // number of L-chunks
#define LC_ 64        // chunk length = L_/C_
#define G_  1024      // chain groups (4 e-chains per group)

typedef float f4_t __attribute__((ext_vector_type(4)));

__device__ __forceinline__ float sigmoidf_(float v) {
    return 1.0f / (1.0f + expf(-v));
}

// Pass 1: per (chunk, 4-chain group) compute local contribution with zero
// inbound state: s = sum_{i} b^(LC-1-i) * a * x[c*LC+i, d]
__global__ __launch_bounds__(256) void ema_pass1(const float* __restrict__ x,
                                                 const float* __restrict__ log_decay,
                                                 float* __restrict__ contrib) {
    const int c  = blockIdx.x >> 2;                         // chunk 0..127
    const int g  = ((blockIdx.x & 3) << 8) + threadIdx.x;   // group 0..1023
    const int d  = g >> 1;
    const int eb = (g & 1) << 2;

    const float a0 = sigmoidf_(log_decay[eb + 0]);
    const float a1 = sigmoidf_(log_decay[eb + 1]);
    const float a2 = sigmoidf_(log_decay[eb + 2]);
    const float a3 = sigmoidf_(log_decay[eb + 3]);
    const float b0 = 1.0f - a0, b1 = 1.0f - a1, b2 = 1.0f - a2, b3 = 1.0f - a3;

    float s0 = 0.f, s1 = 0.f, s2 = 0.f, s3 = 0.f;
    const float* xp = x + (size_t)c * LC_ * D_ + d;
#pragma unroll 4
    for (int i = 0; i < LC_; ++i) {
        const float xv = xp[(size_t)i * D_];
        s0 = fmaf(b0, s0, a0 * xv);
        s1 = fmaf(b1, s1, a1 * xv);
        s2 = fmaf(b2, s2, a2 * xv);
        s3 = fmaf(b3, s3, a3 * xv);
    }
    f4_t r = {s0, s1, s2, s3};
    *(f4_t*)(contrib + (size_t)c * DE_ + 4 * g) = r;
}

// Pass 2: per chain, scan chunk contributions: states[c] = inbound carry for
// chunk c.  states[0] = x[0, d];  states[c+1] = b^LC * states[c] + contrib[c]
__global__ __launch_bounds__(256) void ema_pass2(const float* __restrict__ x,
                                                 const float* __restrict__ log_decay,
                                                 const float* __restrict__ contrib,
                                                 float* __restrict__ states) {
    const int chain = blockIdx.x * 256 + threadIdx.x;  // 0..4095
    const int d = chain >> 3;
    const int e = chain & 7;
    const float a = sigmoidf_(log_decay[e]);
    float B = 1.0f - a;
#pragma unroll
    for (int k = 0; k < 6; ++k) B *= B;   // (1-a)^64

    float s = x[d];                        // initial carry = x[0, d]
    states[chain] = s;
    for (int c = 0; c < C_ - 1; ++c) {
        s = fmaf(B, s, contrib[(size_t)c * DE_ + chain]);
        states[(size_t)(c + 1) * DE_ + chain] = s;
    }
}

// Pass 3: replay each chunk from its correct inbound state, stream output.
__global__ __launch_bounds__(256) void ema_pass3(const float* __restrict__ x,
                                                 const float* __restrict__ log_decay,
                                                 const float* __restrict__ states,
                                                 float* __restrict__ out) {
    const int c  = blockIdx.x >> 2;
    const int g  = ((blockIdx.x & 3) << 8) + threadIdx.x;
    const int d  = g >> 1;
    const int eb = (g & 1) << 2;

    const float a0 = sigmoidf_(log_decay[eb + 0]);
    const float a1 = sigmoidf_(log_decay[eb + 1]);
    const float a2 = sigmoidf_(log_decay[eb + 2]);
    const float a3 = sigmoidf_(log_decay[eb + 3]);
    const float b0 = 1.0f - a0, b1 = 1.0f - a1, b2 = 1.0f - a2, b3 = 1.0f - a3;

    f4_t y = *(const f4_t*)(states + (size_t)c * DE_ + 4 * g);
    const float* xp = x + (size_t)c * LC_ * D_ + d;
    float* op = out + (size_t)c * LC_ * DE_ + 4 * g;

#pragma unroll 4
    for (int i = 0; i < LC_; ++i) {
        const float xv = xp[(size_t)i * D_];
        y.x = fmaf(b0, y.x, a0 * xv);
        y.y = fmaf(b1, y.y, a1 * xv);
        y.z = fmaf(b2, y.z, a2 * xv);
        y.w = fmaf(b3, y.w, a3 * xv);
        __builtin_nontemporal_store(y, (f4_t*)(op + (size_t)i * DE_));
    }
}

// Fallback if workspace is too small: one thread per chain, full serial scan.
__global__ __launch_bounds__(256) void ema_naive(const float* __restrict__ x,
                                                 const float* __restrict__ log_decay,
                                                 float* __restrict__ out) {
    const int chain = blockIdx.x * 256 + threadIdx.x;  // 0..4095
    const int d = chain >> 3;
    const int e = chain & 7;
    const float a = sigmoidf_(log_decay[e]);
    const float b = 1.0f - a;
    float y = x[d];
    for (int l = 0; l < L_; ++l) {
        y = fmaf(b, y, a * x[(size_t)l * D_ + d]);
        out[(size_t)l * DE_ + chain] = y;
    }
}

extern "C" void kernel_launch(void* const* d_in, const int* in_sizes, int n_in,
                              void* d_out, int out_size, void* d_ws, size_t ws_size,
                              hipStream_t stream) {
    const float* x  = (const float*)d_in[0];
    const float* ld = (const float*)d_in[1];
    float* out = (float*)d_out;

    const size_t need = (size_t)2 * C_ * DE_ * sizeof(float);  // 4 MB
    if (ws_size >= need) {
        float* contrib = (float*)d_ws;
        float* states  = contrib + (size_t)C_ * DE_;
        ema_pass1<<<C_ * 4, 256, 0, stream>>>(x, ld, contrib);
        ema_pass2<<<DE_ / 256, 256, 0, stream>>>(x, ld, contrib, states);
        ema_pass3<<<C_ * 4, 256, 0, stream>>>(x, ld, states, out);
    } else {
        ema_naive<<<DE_ / 256, 256, 0, stream>>>(x, ld, out);
    }
}

// Round 2
// 157.012 us; speedup vs baseline: 1.1012x; 1.1012x over previous
//
#include <hip/hip_runtime.h>
#include <math.h>

#define L_  8192
#define D_  512
#define E_  8
#define DE_ 4096      // D_*E_
#define C_  128       // number of L-chunks
#define LC_ 64        // chunk length = L_/C_
#define ST_ 16        // software-pipeline stage width (independent loads in flight)

typedef float f4_t __attribute__((ext_vector_type(4)));

__device__ __forceinline__ float sigmoidf_(float v) {
    return 1.0f / (1.0f + expf(-v));
}

// Pass 1: per (chunk, 4-chain group) compute local contribution with zero
// inbound state: s = sum_i b^(LC-1-i) * a * x[c*LC+i, d]
// Double-buffered 16-wide load stages for deep MLP.
__global__ __launch_bounds__(256) void ema_pass1(const float* __restrict__ x,
                                                 const float* __restrict__ ld,
                                                 float* __restrict__ contrib) {
    const int c  = blockIdx.x >> 2;                        // chunk 0..127
    const int g  = ((blockIdx.x & 3) << 8) + threadIdx.x;  // group 0..1023
    const int d  = g >> 1;
    const int eb = (g & 1) << 2;

    float a[4], b[4];
#pragma unroll
    for (int e = 0; e < 4; ++e) { a[e] = sigmoidf_(ld[eb + e]); b[e] = 1.0f - a[e]; }

    float s[4] = {0.f, 0.f, 0.f, 0.f};
    const float* xp = x + (size_t)c * LC_ * D_ + d;

    float xs[2][ST_];
#pragma unroll
    for (int j = 0; j < ST_; ++j) xs[0][j] = xp[(size_t)j * D_];

#pragma unroll
    for (int st = 0; st < LC_ / ST_; ++st) {
        if (st + 1 < LC_ / ST_) {
#pragma unroll
            for (int j = 0; j < ST_; ++j)
                xs[(st + 1) & 1][j] = xp[(size_t)((st + 1) * ST_ + j) * D_];
        }
#pragma unroll
        for (int j = 0; j < ST_; ++j) {
            const float xv = xs[st & 1][j];
#pragma unroll
            for (int e = 0; e < 4; ++e) s[e] = fmaf(b[e], s[e], a[e] * xv);
        }
    }
    f4_t r = {s[0], s[1], s[2], s[3]};
    *(f4_t*)(contrib + (size_t)c * DE_ + 4 * g) = r;
}

// Pass 2: per chain, scan chunk contributions.
// states[0] = x[0, d]; states[c+1] = (1-a)^LC * states[c] + contrib[c]
// states has C_+1 rows so the last store needs no guard.
__global__ __launch_bounds__(128) void ema_pass2(const float* __restrict__ x,
                                                 const float* __restrict__ ld,
                                                 const float* __restrict__ contrib,
                                                 float* __restrict__ states) {
    const int chain = blockIdx.x * 128 + threadIdx.x;  // 0..4095
    const int d = chain >> 3;
    const int e = chain & 7;
    const float a = sigmoidf_(ld[e]);
    float B = 1.0f - a;
#pragma unroll
    for (int k = 0; k < 6; ++k) B *= B;   // (1-a)^64

    float cb[2][ST_];
#pragma unroll
    for (int j = 0; j < ST_; ++j) cb[0][j] = contrib[(size_t)j * DE_ + chain];

    float s = x[d];                        // initial carry = x[0, d]
    states[chain] = s;

#pragma unroll
    for (int gr = 0; gr < C_ / ST_; ++gr) {
        if (gr + 1 < C_ / ST_) {
#pragma unroll
            for (int j = 0; j < ST_; ++j)
                cb[(gr + 1) & 1][j] = contrib[(size_t)((gr + 1) * ST_ + j) * DE_ + chain];
        }
#pragma unroll
        for (int j = 0; j < ST_; ++j) {
            s = fmaf(B, s, cb[gr & 1][j]);
            states[(size_t)(gr * ST_ + j + 1) * DE_ + chain] = s;
        }
    }
}

// Pass 3: replay each chunk from its correct inbound state, stream output.
// Same staged-load pipeline; nontemporal f4 stores (1 KB/wave, contiguous).
__global__ __launch_bounds__(256) void ema_pass3(const float* __restrict__ x,
                                                 const float* __restrict__ ld,
                                                 const float* __restrict__ states,
                                                 float* __restrict__ out) {
    const int c  = blockIdx.x >> 2;
    const int g  = ((blockIdx.x & 3) << 8) + threadIdx.x;
    const int d  = g >> 1;
    const int eb = (g & 1) << 2;

    float a[4], b[4];
#pragma unroll
    for (int e = 0; e < 4; ++e) { a[e] = sigmoidf_(ld[eb + e]); b[e] = 1.0f - a[e]; }

    f4_t y = *(const f4_t*)(states + (size_t)c * DE_ + 4 * g);
    const float* xp = x + (size_t)c * LC_ * D_ + d;
    float* op = out + (size_t)c * LC_ * DE_ + 4 * g;

    float xs[2][ST_];
#pragma unroll
    for (int j = 0; j < ST_; ++j) xs[0][j] = xp[(size_t)j * D_];

#pragma unroll
    for (int st = 0; st < LC_ / ST_; ++st) {
        if (st + 1 < LC_ / ST_) {
#pragma unroll
            for (int j = 0; j < ST_; ++j)
                xs[(st + 1) & 1][j] = xp[(size_t)((st + 1) * ST_ + j) * D_];
        }
#pragma unroll
        for (int j = 0; j < ST_; ++j) {
            const float xv = xs[st & 1][j];
            y.x = fmaf(b[0], y.x, a[0] * xv);
            y.y = fmaf(b[1], y.y, a[1] * xv);
            y.z = fmaf(b[2], y.z, a[2] * xv);
            y.w = fmaf(b[3], y.w, a[3] * xv);
            __builtin_nontemporal_store(y, (f4_t*)(op + (size_t)(st * ST_ + j) * DE_));
        }
    }
}

// Fallback if workspace is too small: one thread per chain, full serial scan.
__global__ __launch_bounds__(256) void ema_naive(const float* __restrict__ x,
                                                 const float* __restrict__ ld,
                                                 float* __restrict__ out) {
    const int chain = blockIdx.x * 256 + threadIdx.x;  // 0..4095
    const int d = chain >> 3;
    const int e = chain & 7;
    const float a = sigmoidf_(ld[e]);
    const float b = 1.0f - a;
    float y = x[d];
    for (int l = 0; l < L_; ++l) {
        y = fmaf(b, y, a * x[(size_t)l * D_ + d]);
        out[(size_t)l * DE_ + chain] = y;
    }
}

extern "C" void kernel_launch(void* const* d_in, const int* in_sizes, int n_in,
                              void* d_out, int out_size, void* d_ws, size_t ws_size,
                              hipStream_t stream) {
    const float* x  = (const float*)d_in[0];
    const float* ld = (const float*)d_in[1];
    float* out = (float*)d_out;

    // contrib: C_ rows; states: C_+1 rows (extra row = unguarded last store)
    const size_t need = (size_t)(2 * C_ + 1) * DE_ * sizeof(float);
    if (ws_size >= need) {
        float* contrib = (float*)d_ws;
        float* states  = contrib + (size_t)C_ * DE_;
        ema_pass1<<<C_ * 4, 256, 0, stream>>>(x, ld, contrib);
        ema_pass2<<<DE_ / 128, 128, 0, stream>>>(x, ld, contrib, states);
        ema_pass3<<<C_ * 4, 256, 0, stream>>>(x, ld, states, out);
    } else {
        ema_naive<<<DE_ / 256, 256, 0, stream>>>(x, ld, out);
    }
}